// Round 1
// 67.002 us; speedup vs baseline: 1.0122x; 1.0122x over previous
//
#include <hip/hip_runtime.h>

// Problem constants (match reference file)
#define Bn  4
#define Cn  3
#define Hn  224
#define Wn  224
#define Kn  196
#define En  768
#define HW  (Hn * Wn)            // 50176 pixels per (b,c) plane
#define BPB 49                   // pooling blocks per batch
#define NPOOL (Bn * BPB)         // 196 pooling blocks total
#define KC  (Kn * Cn)            // 588 histogram slots

// Kernel 1: per-block segmented partial sums.
// - 1024 contiguous pixels per block (256 thr x 4 px, int4/float4 loads)
// - DUAL privatized LDS histograms (waves 0-1 -> acc[0], waves 2-3 -> acc[1])
//   to halve cross-wave same-address atomic serialization.
// - TRANSPOSED store: partials_T[b][s][j] (s = k*3+c, j = pool block).
//   Scattered 4B stores are fire-and-forget through L2; this buys kernel 2
//   fully contiguous reads of its 147-float reduction row.
// Every byte of partials_T is overwritten -> no workspace pre-zeroing.
__global__ __launch_bounds__(256) void seg_pool_partial(
    const float* __restrict__ img,        // (B,C,H,W)
    const int*   __restrict__ seg,        // (B,H,W)
    float*       __restrict__ partialsT)  // (B, KC, BPB)
{
    __shared__ float acc[2][KC];
    const int tid = threadIdx.x;
    for (int i = tid; i < 2 * KC; i += 256) ((float*)acc)[i] = 0.0f;
    __syncthreads();

    const int batch = blockIdx.x / BPB;
    const int blk   = blockIdx.x % BPB;
    const int p4    = blk * 256 + tid;   // float4 index within a plane
    const int h     = tid >> 7;          // 0 for waves 0-1, 1 for waves 2-3

    const int4*   seg4 = (const int4*)(seg + (size_t)batch * HW);
    const float4* im   = (const float4*)(img + (size_t)batch * Cn * HW);

    const int4   s  = seg4[p4];
    const float4 v0 = im[p4];                 // c = 0 plane
    const float4 v1 = im[HW / 4 + p4];        // c = 1 plane
    const float4 v2 = im[2 * (HW / 4) + p4];  // c = 2 plane

    float* a = acc[h];
    atomicAdd(&a[s.x * 3 + 0], v0.x);
    atomicAdd(&a[s.x * 3 + 1], v1.x);
    atomicAdd(&a[s.x * 3 + 2], v2.x);
    atomicAdd(&a[s.y * 3 + 0], v0.y);
    atomicAdd(&a[s.y * 3 + 1], v1.y);
    atomicAdd(&a[s.y * 3 + 2], v2.y);
    atomicAdd(&a[s.z * 3 + 0], v0.z);
    atomicAdd(&a[s.z * 3 + 1], v1.z);
    atomicAdd(&a[s.z * 3 + 2], v2.z);
    atomicAdd(&a[s.w * 3 + 0], v0.w);
    atomicAdd(&a[s.w * 3 + 1], v1.w);
    atomicAdd(&a[s.w * 3 + 2], v2.w);
    __syncthreads();

    // Transposed store: column j=blk of the (KC x BPB) matrix for this batch.
    float* dst = partialsT + (size_t)batch * KC * BPB + blk;
    for (int sidx = tid; sidx < KC; sidx += 256)
        dst[(size_t)sidx * BPB] = acc[0][sidx] + acc[1][sidx];
}

// Kernel 2: 196 blocks x 256 threads; each WAVE owns one (b,k).
// No LDS, no __syncthreads. Contiguous 147-float row load, 6-step
// __shfl_xor butterfly (all 64 lanes), then coalesced float4 GEMV row:
// out[b,k,e] = (1/HW) * sum_c pooled_c * W[c,e] + bias[e].
__global__ __launch_bounds__(256) void embed_kernel(
    const float* __restrict__ partialsT,  // (B, KC, BPB)
    const float* __restrict__ Wm,         // (C,E)
    const float* __restrict__ bias,       // (E,)
    float*       __restrict__ out)        // (B,K,E)
{
    const int tid  = threadIdx.x;
    const int lane = tid & 63;
    const int wv   = tid >> 6;                    // 4 waves -> 4 k's per block
    const int b    = blockIdx.x / BPB;
    const int k    = (blockIdx.x % BPB) * 4 + wv; // covers k = 0..195

    // Rows s = k*3 .. k*3+2 are contiguous: 147 floats.
    const float* row = partialsT + ((size_t)b * KC + k * 3) * BPB;
    float a0 = (lane < BPB) ? row[lane]           : 0.0f;
    float a1 = (lane < BPB) ? row[BPB + lane]     : 0.0f;
    float a2 = (lane < BPB) ? row[2 * BPB + lane] : 0.0f;

    #pragma unroll
    for (int off = 32; off > 0; off >>= 1) {
        a0 += __shfl_xor(a0, off, 64);
        a1 += __shfl_xor(a1, off, 64);
        a2 += __shfl_xor(a2, off, 64);
    }
    const float p0 = a0 * (1.0f / (float)HW);
    const float p1 = a1 * (1.0f / (float)HW);
    const float p2 = a2 * (1.0f / (float)HW);

    const float4* W4 = (const float4*)Wm;    // row c starts at c*192
    const float4* B4 = (const float4*)bias;
    float4* O4 = (float4*)out + ((size_t)b * Kn + k) * (En / 4);

    #pragma unroll
    for (int part = 0; part < 3; ++part) {
        const int idx = part * 64 + lane;    // coalesced across the wave
        const float4 w0 = W4[idx];
        const float4 w1 = W4[192 + idx];
        const float4 w2 = W4[384 + idx];
        const float4 bb = B4[idx];
        float4 r;
        r.x = p0 * w0.x + p1 * w1.x + p2 * w2.x + bb.x;
        r.y = p0 * w0.y + p1 * w1.y + p2 * w2.y + bb.y;
        r.z = p0 * w0.z + p1 * w1.z + p2 * w2.z + bb.z;
        r.w = p0 * w0.w + p1 * w1.w + p2 * w2.w + bb.w;
        O4[idx] = r;
    }
}

extern "C" void kernel_launch(void* const* d_in, const int* in_sizes, int n_in,
                              void* d_out, int out_size, void* d_ws, size_t ws_size,
                              hipStream_t stream) {
    const float* img  = (const float*)d_in[0];  // (4,3,224,224) fp32
    const int*   seg  = (const int*)  d_in[1];  // (4,224,224) int32
    const float* Wm   = (const float*)d_in[2];  // (3,768) fp32
    const float* bias = (const float*)d_in[3];  // (768,) fp32
    float* out       = (float*)d_out;           // (4,196,768) fp32
    float* partialsT = (float*)d_ws;            // (B,KC,BPB) = 461 KB, fully overwritten

    seg_pool_partial<<<NPOOL, 256, 0, stream>>>(img, seg, partialsT);
    embed_kernel<<<NPOOL, 256, 0, stream>>>(partialsT, Wm, bias, out);
}